// Round 1
// baseline (902.533 us; speedup 1.0000x reference)
//
#include <hip/hip_runtime.h>
#include <math.h>

namespace {

constexpr int kN = 200;   // nodes
constexpr int kP = 200;   // patterns
constexpr int kT = 9000;  // time
constexpr int kB = 32;    // batch
constexpr int kS = 360;   // pooled length (T/25)
constexpr int kH = 128;   // hidden
constexpr int kWC = 72;   // window-chunks per b (5 windows of 25 each -> 125 t per block)

// ---------------------------------------------------------------------------
// Workspace layout (bytes):
// 0        meanh   [B*H]  f32   (zeroed)
// 16384    gsums   [2]    f32   (zeroed)  [0]=sum np_^2  [1]=sum tp^2
// 16400    diag    [B*P]  f32
// 42000    ssq_tp  [P]    f32
// 42800    t3val   [P*3]  f32
// 45200    t3sign  [P*3]  f32
// 47600    t3idx   [P*3]  i32
// 50000    np_     [P*N]  f32
// 210000   inv_rn  [B*T]  f32
// 1362000  posval  [B*P*S] f32
// 10578000 negval  [B*P*S] f32
// 19794000 posi    [B*P*S] u16
// 24402000 negi    [B*P*S] u16    (total ~29 MB)
// ---------------------------------------------------------------------------

__device__ inline float wave_sum(float v) {
#pragma unroll
  for (int off = 32; off >= 1; off >>= 1) v += __shfl_xor(v, off);
  return v;
}

// -------------------- 1. pattern prep (one wave per pattern row) -----------
__global__ __launch_bounds__(64) void k_pattern(
    const float* __restrict__ pat, float* __restrict__ npm,
    float* __restrict__ t3val, int* __restrict__ t3idx,
    float* __restrict__ t3sign, float* __restrict__ ssq_tp,
    float* __restrict__ gsums) {
  const int p = blockIdx.x, lane = threadIdx.x;
  __shared__ float row[kN];
  float v[4];
  float ssq = 0.f;
#pragma unroll
  for (int j = 0; j < 4; ++j) {
    int n = lane + 64 * j;
    float val = 0.f;
    if (n < kN) {
      float a = pat[p * kN + n];
      val = (n == p) ? 1.0f : tanhf(a);
    }
    v[j] = val;
    ssq += val * val;
  }
  ssq = wave_sum(ssq);
  const float inv = 1.0f / sqrtf(ssq + 1e-9f);
  float ssqn = 0.f;
#pragma unroll
  for (int j = 0; j < 4; ++j) {
    int n = lane + 64 * j;
    if (n < kN) {
      float nv = v[j] * inv;
      npm[p * kN + n] = nv;
      row[n] = nv;
      ssqn += nv * nv;
    }
  }
  ssqn = wave_sum(ssqn);
  __syncthreads();
  if (lane == 0) {
    // top-3 of |row|, first-occurrence tie-break (matches jax.lax.top_k)
    float v1 = -1.f, v2 = -1.f, v3 = -1.f;
    int i1 = 0, i2 = 0, i3 = 0;
    for (int n = 0; n < kN; ++n) {
      float a = fabsf(row[n]);
      if (a > v1)      { v3 = v2; i3 = i2; v2 = v1; i2 = i1; v1 = a; i1 = n; }
      else if (a > v2) { v3 = v2; i3 = i2; v2 = a; i2 = n; }
      else if (a > v3) { v3 = a; i3 = n; }
    }
    float a1 = row[i1], a2 = row[i2], a3 = row[i3];
    t3idx[p * 3 + 0] = i1; t3idx[p * 3 + 1] = i2; t3idx[p * 3 + 2] = i3;
    t3val[p * 3 + 0] = a1; t3val[p * 3 + 1] = a2; t3val[p * 3 + 2] = a3;
    t3sign[p * 3 + 0] = (a1 > 0.f) ? 1.f : ((a1 < 0.f) ? -1.f : 0.f);
    t3sign[p * 3 + 1] = (a2 > 0.f) ? 1.f : ((a2 < 0.f) ? -1.f : 0.f);
    t3sign[p * 3 + 2] = (a3 > 0.f) ? 1.f : ((a3 < 0.f) ? -1.f : 0.f);
    float st = a1 * a1 + a2 * a2 + a3 * a3;
    ssq_tp[p] = st;
    atomicAdd(&gsums[0], ssqn);
    atomicAdd(&gsums[1], st);
  }
}

// -------------------- 2. per-(b,t) frame inverse norms ---------------------
__global__ __launch_bounds__(256) void k_rownorm(const float* __restrict__ x,
                                                 float* __restrict__ inv_rn) {
  int idx = blockIdx.x * 256 + threadIdx.x;
  if (idx >= kB * kT) return;
  int b = idx / kT, t = idx % kT;
  const float* xp = x + (size_t)b * kN * kT + t;
  float s0 = 0.f, s1 = 0.f, s2 = 0.f, s3 = 0.f;
  for (int n = 0; n < kN; n += 4) {
    float x0 = xp[(size_t)(n + 0) * kT];
    float x1 = xp[(size_t)(n + 1) * kT];
    float x2 = xp[(size_t)(n + 2) * kT];
    float x3 = xp[(size_t)(n + 3) * kT];
    s0 += x0 * x0; s1 += x1 * x1; s2 += x2 * x2; s3 += x3 * x3;
  }
  float s = (s0 + s1) + (s2 + s3);
  inv_rn[idx] = 1.0f / sqrtf(s + 1e-9f);
}

// -------------------- 3. fused scores GEMM + window-25 max-pool ------------
// block: (b, wchunk of 5 windows = 125 t). 512 threads: tid<500 active,
// thread = (p2 = tid%100, w = tid/100); owns patterns {p2, p2+100}, window w.
__global__ __launch_bounds__(512, 2) void k_scores_pool(
    const float* __restrict__ x, const float* __restrict__ npm,
    const float* __restrict__ inv_rn,
    float* __restrict__ posval, float* __restrict__ negval,
    unsigned short* __restrict__ posi, unsigned short* __restrict__ negi) {
  const int bid = blockIdx.x;
  const int b = bid / kWC, wc = bid % kWC;
  const int t0 = wc * 125;
  __shared__ float ps[kP * 51];    // np_ chunk, pitch 51 (conflict-free)
  __shared__ float xs[50 * 140];   // x chunk, 5 windows padded to 28 floats
  const int tid = threadIdx.x;
  const int p2 = tid % 100, w = tid / 100;
  const bool active = tid < 500;
  float accA[25], accB[25];
#pragma unroll
  for (int t = 0; t < 25; ++t) { accA[t] = 0.f; accB[t] = 0.f; }
  const size_t xb = (size_t)b * kN * kT;

  for (int nc = 0; nc < 4; ++nc) {   // 4 chunks of 50 n
    __syncthreads();
    for (int i = tid; i < kP * 50; i += 512) {
      int p = i / 50, n = i % 50;
      ps[p * 51 + n] = npm[p * kN + nc * 50 + n];
    }
    for (int i = tid; i < 50 * 125; i += 512) {
      int n = i / 125, tt = i % 125;
      xs[n * 140 + (tt / 25) * 28 + (tt % 25)] =
          x[xb + (size_t)(nc * 50 + n) * kT + t0 + tt];
    }
    __syncthreads();
    if (active) {
      for (int n = 0; n < 50; ++n) {
        float va = ps[p2 * 51 + n];
        float vb = ps[(p2 + 100) * 51 + n];
        const float* xr = &xs[n * 140 + w * 28];
#pragma unroll
        for (int t = 0; t < 25; ++t) {
          float xv = xr[t];
          accA[t] = fmaf(va, xv, accA[t]);
          accB[t] = fmaf(vb, xv, accB[t]);
        }
      }
    }
  }

  if (active) {
    const int tg0 = t0 + w * 25;
    float bA = -1e30f, bnA = -1e30f, bB = -1e30f, bnB = -1e30f;
    int iA = 0, inA = 0, iB = 0, inB = 0;
#pragma unroll
    for (int t = 0; t < 25; ++t) {
      float iv = inv_rn[b * kT + tg0 + t];
      float sA = accA[t] * iv, sB = accB[t] * iv;
      if (sA > bA)   { bA = sA;  iA = t; }
      if (-sA > bnA) { bnA = -sA; inA = t; }
      if (sB > bB)   { bB = sB;  iB = t; }
      if (-sB > bnB) { bnB = -sB; inB = t; }
    }
    const int s = wc * 5 + w;
    const size_t oA = (size_t)(b * kP + p2) * kS + s;
    const size_t oB = (size_t)(b * kP + p2 + 100) * kS + s;
    posval[oA] = bA;  negval[oA] = bnA;
    posval[oB] = bB;  negval[oB] = bnB;
    posi[oA] = (unsigned short)(tg0 + iA);
    negi[oA] = (unsigned short)(tg0 + inA);
    posi[oB] = (unsigned short)(tg0 + iB);
    negi[oB] = (unsigned short)(tg0 + inB);
  }
}

// -------------------- 4. avg_sel (3 masked cols) + scores2 + diag ----------
// one wave per (b,p); 4 waves per block
__global__ __launch_bounds__(256) void k_avgsel(
    const float* __restrict__ x, const float* __restrict__ inv_rn,
    const unsigned short* __restrict__ posi, const unsigned short* __restrict__ negi,
    const float* __restrict__ posval, const float* __restrict__ negval,
    const int* __restrict__ t3idx, const float* __restrict__ t3val,
    const float* __restrict__ ssq_tp, float* __restrict__ diag) {
  const int gw = blockIdx.x * 4 + (threadIdx.x >> 6);
  const int lane = threadIdx.x & 63;
  const int b = gw / kP, p = gw % kP;
  const int n0 = t3idx[p * 3 + 0], n1 = t3idx[p * 3 + 1], n2 = t3idx[p * 3 + 2];
  const float* xb = x + (size_t)b * kN * kT;
  const float* ivb = inv_rn + b * kT;
  const size_t base = (size_t)(b * kP + p) * kS;
  float a0 = 0.f, a1 = 0.f, a2 = 0.f, sp = 0.f, sn = 0.f;
  for (int s = lane; s < kS; s += 64) {
    int tp_ = posi[base + s], tn_ = negi[base + s];
    float ivp = ivb[tp_], ivn = ivb[tn_];
    a0 += xb[(size_t)n0 * kT + tp_] * ivp - xb[(size_t)n0 * kT + tn_] * ivn;
    a1 += xb[(size_t)n1 * kT + tp_] * ivp - xb[(size_t)n1 * kT + tn_] * ivn;
    a2 += xb[(size_t)n2 * kT + tp_] * ivp - xb[(size_t)n2 * kT + tn_] * ivn;
    sp += posval[base + s];
    sn += negval[base + s];
  }
  a0 = wave_sum(a0); a1 = wave_sum(a1); a2 = wave_sum(a2);
  sp = wave_sum(sp); sn = wave_sum(sn);
  if (lane == 0) {
    const float c0 = 8.16496580927726f;  // sqrt(200/3)
    float T0 = c0 * a0 / 360.0f / 2.0f;
    float T1 = c0 * a1 / 360.0f / 2.0f;
    float T2 = c0 * a2 / 360.0f / 2.0f;
    float st = T0 * T0 + T1 * T1 + T2 * T2;
    float itf = 1.0f / sqrtf(st + 1e-9f);
    float itp = 1.0f / sqrtf(ssq_tp[p] + 1e-9f);
    float s2 = T0 * itf * (t3val[p * 3 + 0] * itp) +
               T1 * itf * (t3val[p * 3 + 1] * itp) +
               T2 * itf * (t3val[p * 3 + 2] * itp);
    float fs = (sp / 360.0f + sn / 360.0f) * 0.5f;
    diag[b * kP + p] = fs + 0.25f * (s2 * 0.12247448713915890f);  // sqrt(3/200)
  }
}

// -------------------- 5. graphs build (one block per b) --------------------
__global__ __launch_bounds__(256) void k_graphs(
    const float* __restrict__ diag, const int* __restrict__ t3idx,
    const float* __restrict__ t3sign, float* __restrict__ gout) {
  const int b = blockIdx.x, tid = threadIdx.x;
  __shared__ float g[kN * kN];  // 156.25 KiB
  for (int i = tid; i < kN * kN; i += 256) g[i] = 0.f;
  __syncthreads();
  for (int p = tid; p < kP; p += 256) {
    float d = diag[b * kP + p];
    int i0 = t3idx[p * 3 + 0], i1 = t3idx[p * 3 + 1], i2 = t3idx[p * 3 + 2];
    float r0 = t3sign[p * 3 + 0] * (1.0f / 3.0f);
    float r1 = t3sign[p * 3 + 1] * (1.0f / 3.0f);
    float r2 = t3sign[p * 3 + 2] * (1.0f / 3.0f);
    int   ii[3] = {i0, i1, i2};
    float rr[3] = {r0, r1, r2};
#pragma unroll
    for (int j = 0; j < 3; ++j)
#pragma unroll
      for (int k = 0; k < 3; ++k)
        atomicAdd(&g[ii[j] * kN + ii[k]], d * rr[j] * rr[k]);
  }
  __syncthreads();
  float* go = gout + (size_t)b * kN * kN;
  for (int i = tid; i < kN * kN; i += 256) {
    int n = i / kN, m = i % kN;
    float nd = (n == m) ? 1.0f : 3.0f;
    go[i] = g[i] * nd / 0.6f;
  }
}

// -------------------- 6. classifier: h=relu(g@W1+b1), partial mean ---------
__global__ __launch_bounds__(256) void k_classifier(
    const float* __restrict__ graphs, const float* __restrict__ W1,
    const float* __restrict__ b1, float* __restrict__ meanh) {
  const int b = blockIdx.x / 8, nc = blockIdx.x % 8;
  const int tid = threadIdx.x;
  __shared__ float g[25][kN];
  for (int i = tid; i < 25 * kN; i += 256) {
    int n = i / kN, m = i % kN;
    g[n][m] = graphs[(size_t)b * kN * kN + (size_t)(nc * 25 + n) * kN + m];
  }
  __syncthreads();
  const int hh = tid & 127, grp = tid >> 7;  // 0/1
  const int ns = (grp == 0) ? 0 : 13, ne = (grp == 0) ? 13 : 25;
  float sumh = 0.f;
  for (int n = ns; n < ne; ++n) {
    float acc = b1[hh];
    for (int m = 0; m < kN; ++m) acc = fmaf(g[n][m], W1[m * kH + hh], acc);
    sumh += fmaxf(acc, 0.f);
  }
  atomicAdd(&meanh[b * kH + hh], sumh);
}

// -------------------- 7. head: out = mean_h @ W2 + b2, and norm ------------
__global__ __launch_bounds__(64) void k_final(
    const float* __restrict__ meanh, const float* __restrict__ W2,
    const float* __restrict__ b2, const float* __restrict__ gsums,
    float* __restrict__ out) {
  const int tid = threadIdx.x;
  if (tid < 64) {
    int b = tid >> 1, k = tid & 1;
    float acc = 0.f;
    for (int h = 0; h < kH; ++h) {
      float mv = meanh[b * kH + h] / 200.0f;
      acc = fmaf(mv, W2[h * 2 + k], acc);
    }
    out[b * 2 + k] = acc + b2[k];
  }
  if (tid == 0) {
    float r = 1.0f - sqrtf(gsums[1]) / sqrtf(gsums[0]);
    out[64] = r * r;
  }
}

}  // namespace

extern "C" void kernel_launch(void* const* d_in, const int* in_sizes, int n_in,
                              void* d_out, int out_size, void* d_ws, size_t ws_size,
                              hipStream_t stream) {
  const float* x   = (const float*)d_in[0];
  // d_in[1] = length (always 9000, shapes static)
  const float* pat = (const float*)d_in[2];
  const float* W1  = (const float*)d_in[3];
  const float* b1  = (const float*)d_in[4];
  const float* W2  = (const float*)d_in[5];
  const float* b2  = (const float*)d_in[6];
  float* out = (float*)d_out;

  char* ws = (char*)d_ws;
  float* meanh  = (float*)(ws + 0);
  float* gsums  = (float*)(ws + 16384);
  float* diag   = (float*)(ws + 16400);
  float* ssqtp  = (float*)(ws + 42000);
  float* t3val  = (float*)(ws + 42800);
  float* t3sign = (float*)(ws + 45200);
  int*   t3idx  = (int*)(ws + 47600);
  float* npm    = (float*)(ws + 50000);
  float* invrn  = (float*)(ws + 210000);
  float* posval = (float*)(ws + 1362000);
  float* negval = (float*)(ws + 10578000);
  unsigned short* posi = (unsigned short*)(ws + 19794000);
  unsigned short* negi = (unsigned short*)(ws + 24402000);

  hipMemsetAsync(d_ws, 0, 16392, stream);  // meanh + gsums accumulators
  k_pattern<<<kP, 64, 0, stream>>>(pat, npm, t3val, t3idx, t3sign, ssqtp, gsums);
  k_rownorm<<<(kB * kT) / 256, 256, 0, stream>>>(x, invrn);
  k_scores_pool<<<kB * kWC, 512, 0, stream>>>(x, npm, invrn, posval, negval, posi, negi);
  k_avgsel<<<(kB * kP) / 4, 256, 0, stream>>>(x, invrn, posi, negi, posval, negval,
                                              t3idx, t3val, ssqtp, diag);
  k_graphs<<<kB, 256, 0, stream>>>(diag, t3idx, t3sign, out + 65);
  k_classifier<<<kB * 8, 256, 0, stream>>>(out + 65, W1, b1, meanh);
  k_final<<<1, 64, 0, stream>>>(meanh, W2, b2, gsums, out);
}